// Round 12
// baseline (1839.002 us; speedup 1.0000x reference)
//
#include <hip/hip_runtime.h>
#include <hip/hip_bf16.h>

#define B_ 2
#define H_ 16
#define S_ 2048
#define D_ 64
#define PSTR 2056   // bf16 elems/row; 4112B stride

typedef float f32x4 __attribute__((ext_vector_type(4)));
typedef short s16x8 __attribute__((ext_vector_type(8)));
typedef short s16x4 __attribute__((ext_vector_type(4)));

__device__ __forceinline__ short f2bf(float f) {
  unsigned u = __float_as_uint(f);
  u += 0x7FFFu + ((u >> 16) & 1u);
  return (short)(u >> 16);
}
__device__ __forceinline__ float bf2f(short s) {
  return __uint_as_float(((unsigned)(unsigned short)s) << 16);
}

// p = exp(50*tanh(a/400) - 50) -> exp2(a*(k1+y*k2+y^2*k3) - C), y=a^2
__device__ __forceinline__ float softcap_p(float a) {
  const float k1 = 0.18033688011f;
  const float k2 = -3.7570183e-07f;
  const float k3 = 9.3926761e-13f;
  const float C  = 72.134752044f;
  float y = a * a;
  float t = __builtin_fmaf(y, k3, k2);
  t = __builtin_fmaf(y, t, k1);
  float arg = __builtin_fmaf(a, t, -C);
  arg = fminf(arg, 0.f);
  return exp2f(arg);
}

// ---------------- prep: f32 -> bf16 (Q, K) ----------------
__global__ __launch_bounds__(256) void prep_qk(const float* __restrict__ q,
                                               const float* __restrict__ k,
                                               short* __restrict__ qbf,
                                               short* __restrict__ kbf) {
  size_t i = ((size_t)blockIdx.x * 256 + threadIdx.x) * 8;
  const f32x4* qa = (const f32x4*)(q + i);
  const f32x4* ka = (const f32x4*)(k + i);
  f32x4 a0 = __builtin_nontemporal_load(qa);
  f32x4 a1 = __builtin_nontemporal_load(qa + 1);
  f32x4 b0 = __builtin_nontemporal_load(ka);
  f32x4 b1 = __builtin_nontemporal_load(ka + 1);
  s16x8 oq, ok;
  #pragma unroll
  for (int e = 0; e < 4; ++e) {
    oq[e] = f2bf(a0[e]); oq[4 + e] = f2bf(a1[e]);
    ok[e] = f2bf(b0[e]); ok[4 + e] = f2bf(b1[e]);
  }
  *(s16x8*)(qbf + i) = oq;
  *(s16x8*)(kbf + i) = ok;
}

// ---------------- prep: V -> bf16 transposed Vt[bh][d][j] ----------------
__global__ __launch_bounds__(256) void prep_v(const float* __restrict__ v,
                                              short* __restrict__ vt) {
  __shared__ float tile[64][65];
  const int tid = threadIdx.x;
  const int j0 = blockIdx.x * 64;
  const int bh = blockIdx.y;
  const float* vh = v + (size_t)bh * S_ * D_;
  #pragma unroll
  for (int it = 0; it < 16; ++it) {
    int idx = it * 256 + tid;
    int row = idx >> 6, col = idx & 63;
    tile[row][col] = __builtin_nontemporal_load(&vh[(size_t)(j0 + row) * D_ + col]);
  }
  __syncthreads();
  short* vth = vt + (size_t)bh * D_ * S_;
  #pragma unroll
  for (int it = 0; it < 16; ++it) {
    int idx = it * 256 + tid;
    int d = idx >> 6, jj = idx & 63;
    vth[(size_t)d * S_ + j0 + jj] = f2bf(tile[jj][d]);
  }
}

// ---------------- ablation-instrumented fused kernel (R9 structure) ----------------
// VAR: 0 = full (real)   1 = noST (skip attn stores)
//      2 = noPV (skip PV/pvred/out)   3 = QK+softcap+rowsum floor only
// REPS: repeat whole body (to exceed rocprof top-5 visibility threshold).
template <bool PRE, int VAR, int REPS>
__global__ __launch_bounds__(512, 2) void attend_abl(
    const float* __restrict__ q, const float* __restrict__ k,
    const float* __restrict__ v, const int* __restrict__ mask,
    const short* __restrict__ qbf, const short* __restrict__ kbf,
    const short* __restrict__ vt,
    float* __restrict__ out, float* __restrict__ attn) {
  __shared__ short strip[16 * PSTR];
  __shared__ float ls_rs[8][16];
  __shared__ float ls_rinv[16];

  const int tid  = threadIdx.x;
  const int wv   = tid >> 6;
  const int lane = tid & 63;
  const int lg   = lane >> 4;
  const int li   = lane & 15;

  const unsigned flat = blockIdx.y * gridDim.x + blockIdx.x;
  const unsigned swz  = (flat & 7) * 512 + (flat >> 3);
  const int q0 = (int)(swz & 127) * 16;
  const int bh = (int)(swz >> 7);
  const int b  = bh >> 4;
  const int* mrow = mask + (size_t)b * S_;

  s16x8 qf0, qf1;
  if constexpr (PRE) {
    const short* qr = qbf + ((size_t)bh * S_ + q0 + li) * D_ + lg * 8;
    qf0 = *(const s16x8*)qr;
    qf1 = *(const s16x8*)(qr + 32);
  } else {
    const float* qr = q + ((size_t)bh * S_ + q0 + li) * D_ + lg * 8;
    #pragma unroll
    for (int e = 0; e < 8; ++e) { qf0[e] = f2bf(qr[e]); qf1[e] = f2bf(qr[32 + e]); }
  }

  const short* kbase = PRE ? (kbf + (size_t)bh * S_ * D_) : nullptr;
  s16x8 kf[8];
  auto ldK = [&](int cc) {
    const int jcc = cc * 512 + wv * 64;
    #pragma unroll
    for (int n = 0; n < 4; ++n) {
      const short* kr = kbase + (size_t)(jcc + n * 16 + li) * D_ + lg * 8;
      kf[2 * n]     = *(const s16x8*)kr;
      kf[2 * n + 1] = *(const s16x8*)(kr + 32);
    }
  };

  for (int rep = 0; rep < REPS; ++rep) {
    if constexpr (PRE) ldK(0);

    float rs[4] = {0.f, 0.f, 0.f, 0.f};
    f32x4 pvacc[4];
    #pragma unroll
    for (int m = 0; m < 4; ++m) pvacc[m] = (f32x4){0.f, 0.f, 0.f, 0.f};

    #pragma unroll
    for (int c = 0; c < 4; ++c) {
      const int jc = c * 512 + wv * 64;

      f32x4 acc[4];
      #pragma unroll
      for (int n = 0; n < 4; ++n) acc[n] = (f32x4){0.f, 0.f, 0.f, 0.f};
      if constexpr (PRE) {
        #pragma unroll
        for (int n = 0; n < 4; ++n) {
          acc[n] = __builtin_amdgcn_mfma_f32_16x16x32_bf16(qf0, kf[2 * n], acc[n], 0, 0, 0);
          acc[n] = __builtin_amdgcn_mfma_f32_16x16x32_bf16(qf1, kf[2 * n + 1], acc[n], 0, 0, 0);
        }
        if (c < 3) ldK(c + 1);
      } else {
        #pragma unroll
        for (int n = 0; n < 4; ++n) {
          const float* kr = k + ((size_t)bh * S_ + jc + n * 16 + li) * D_ + lg * 8;
          s16x8 k0, k1;
          #pragma unroll
          for (int e = 0; e < 8; ++e) { k0[e] = f2bf(kr[e]); k1[e] = f2bf(kr[32 + e]); }
          acc[n] = __builtin_amdgcn_mfma_f32_16x16x32_bf16(qf0, k0, acc[n], 0, 0, 0);
          acc[n] = __builtin_amdgcn_mfma_f32_16x16x32_bf16(qf1, k1, acc[n], 0, 0, 0);
        }
      }

      #pragma unroll
      for (int n = 0; n < 4; ++n) {
        const int j = jc + n * 16 + li;
        const bool keep = mrow[j] != 0;
        #pragma unroll
        for (int r = 0; r < 4; ++r) {
          float pp = softcap_p(acc[n][r]);
          float pv_ = keep ? pp : 0.f;
          rs[r] += pv_;
          if constexpr (VAR != 3) strip[(lg * 4 + r) * PSTR + j] = f2bf(pv_);
        }
      }

      if constexpr (VAR == 0 || VAR == 1) {
        #pragma unroll
        for (int ks = 0; ks < 2; ++ks) {
          s16x8 pa = *(const s16x8*)&strip[li * PSTR + jc + ks * 32 + lg * 8];
          #pragma unroll
          for (int m = 0; m < 4; ++m) {
            s16x8 vb;
            if constexpr (PRE) {
              vb = *(const s16x8*)(vt + ((size_t)bh * D_ + m * 16 + li) * S_ + jc + ks * 32 + lg * 8);
            } else {
              const float* vp = v + (size_t)bh * S_ * D_ + (size_t)(jc + ks * 32 + lg * 8) * D_ + m * 16 + li;
              #pragma unroll
              for (int e = 0; e < 8; ++e) vb[e] = f2bf(vp[(size_t)e * D_]);
            }
            pvacc[m] = __builtin_amdgcn_mfma_f32_16x16x32_bf16(pa, vb, pvacc[m], 0, 0, 0);
          }
        }
      }
    }

    // rowsum reduce (identical in all variants)
    #pragma unroll
    for (int r = 0; r < 4; ++r) {
      #pragma unroll
      for (int m = 1; m < 16; m <<= 1) rs[r] += __shfl_xor(rs[r], m, 64);
    }
    if (li == 0) {
      #pragma unroll
      for (int r = 0; r < 4; ++r) ls_rs[wv][lg * 4 + r] = rs[r];
    }
    __syncthreads();
    if (tid < 16) {
      float ssum = 0.f;
      #pragma unroll
      for (int w = 0; w < 8; ++w) ssum += ls_rs[w][tid];
      ls_rinv[tid] = (ssum > 0.f) ? 1.f / ssum : 0.f;
    }
    __syncthreads();

    if constexpr (VAR == 3) {
      // keep rowsum live: tiny write into out (overwritten by real kernel later)
      if (tid < 16) out[(size_t)flat * 16 + tid] = ls_rinv[tid];
    }

    if constexpr (VAR == 0 || VAR == 2) {
      float* abase = attn + ((size_t)bh * S_ + q0) * S_;
      #pragma unroll
      for (int rr = 0; rr < 2; ++rr) {
        const int row = wv * 2 + rr;
        const float rv = ls_rinv[row];
        const short* srow = &strip[row * PSTR];
        float* arow = abase + (size_t)row * S_;
        #pragma unroll
        for (int it = 0; it < 8; ++it) {
          s16x4 pb = *(const s16x4*)&srow[it * 256 + lane * 4];
          f32x4 a;
          a[0] = bf2f(pb[0]) * rv; a[1] = bf2f(pb[1]) * rv;
          a[2] = bf2f(pb[2]) * rv; a[3] = bf2f(pb[3]) * rv;
          __builtin_nontemporal_store(a, (f32x4*)(arow + it * 256 + lane * 4));
        }
      }
    }

    if constexpr (VAR == 0 || VAR == 1) {
      __syncthreads();
      float (*pvred)[16][64] = (float (*)[16][64])strip;
      #pragma unroll
      for (int m = 0; m < 4; ++m)
        #pragma unroll
        for (int r = 0; r < 4; ++r)
          pvred[wv][lg * 4 + r][m * 16 + li] = pvacc[m][r];
      __syncthreads();
      #pragma unroll
      for (int h = 0; h < 2; ++h) {
        const int idx = h * 512 + tid;
        const int qq = idx >> 6, d = idx & 63;
        float ssum = 0.f;
        #pragma unroll
        for (int w = 0; w < 8; ++w) ssum += pvred[w][qq][d];
        out[((size_t)bh * S_ + q0 + qq) * D_ + d] = ssum * ls_rinv[qq];
      }
      __syncthreads();   // strip reuse safe across reps
    } else {
      __syncthreads();
    }
  }
}

extern "C" void kernel_launch(void* const* d_in, const int* in_sizes, int n_in,
                              void* d_out, int out_size, void* d_ws, size_t ws_size,
                              hipStream_t stream) {
  const float* q = (const float*)d_in[0];
  const float* k = (const float*)d_in[1];
  const float* v = (const float*)d_in[2];
  const int* mask = (const int*)d_in[3];

  float* out  = (float*)d_out;
  const size_t nel = (size_t)B_ * H_ * S_ * D_;
  float* attn = out + nel;

  dim3 grid(S_ / 16, B_ * H_);
  const size_t need = nel * 2 * 3;

  if (ws_size >= need) {
    short* qbf = (short*)d_ws;
    short* kbf = qbf + nel;
    short* vtp = kbf + nel;
    prep_qk<<<(int)(nel / (256 * 8)), 256, 0, stream>>>(q, k, qbf, kbf);
    prep_v<<<dim3(S_ / 64, B_ * H_), 256, 0, stream>>>(v, vtp);
    // --- diagnostic ablations (outputs overwritten by the real kernel below) ---
    attend_abl<true, 3, 5><<<grid, 512, 0, stream>>>(q, k, v, mask, qbf, kbf, vtp, out, attn);
    attend_abl<true, 2, 3><<<grid, 512, 0, stream>>>(q, k, v, mask, qbf, kbf, vtp, out, attn);
    attend_abl<true, 1, 3><<<grid, 512, 0, stream>>>(q, k, v, mask, qbf, kbf, vtp, out, attn);
    // --- real kernel (last: produces the final correct output) ---
    attend_abl<true, 0, 1><<<grid, 512, 0, stream>>>(q, k, v, mask, qbf, kbf, vtp, out, attn);
  } else {
    attend_abl<false, 0, 1><<<grid, 512, 0, stream>>>(q, k, v, mask, nullptr, nullptr, nullptr, out, attn);
  }
}

// Round 13
// 317.939 us; speedup vs baseline: 5.7841x; 5.7841x over previous
//
#include <hip/hip_runtime.h>
#include <hip/hip_bf16.h>

#define B_ 2
#define H_ 16
#define S_ 2048
#define D_ 64
#define PSTR 2056   // bf16 elems/row; 4112B stride -> 16B-aligned rows

typedef float f32x4 __attribute__((ext_vector_type(4)));
typedef short s16x8 __attribute__((ext_vector_type(8)));
typedef short s16x4 __attribute__((ext_vector_type(4)));

__device__ __forceinline__ short f2bf(float f) {
  unsigned u = __float_as_uint(f);
  u += 0x7FFFu + ((u >> 16) & 1u);   // RTNE (finite inputs)
  return (short)(u >> 16);
}
__device__ __forceinline__ float bf2f(short s) {
  return __uint_as_float(((unsigned)(unsigned short)s) << 16);
}

// softcap+exp poly: p = exp(50*tanh(a/400)-50) -> exp2(a*(k1+y*k2+y^2*k3)-C)
__device__ __forceinline__ float softcap_p(float a) {
  const float k1 = 0.18033688011f;    // log2e/8
  const float k2 = -3.7570183e-07f;   // -log2e*50/(3*400^3)
  const float k3 = 9.3926761e-13f;    // +log2e*100/(15*400^5)
  const float C  = 72.134752044f;     // 50*log2e
  float y = a * a;
  float t = __builtin_fmaf(y, k3, k2);
  t = __builtin_fmaf(y, t, k1);
  float arg = __builtin_fmaf(a, t, -C);
  arg = fminf(arg, 0.f);
  return exp2f(arg);
}

// ---------------- prep: f32 -> bf16 (Q, K) ----------------
__global__ __launch_bounds__(256) void prep_qk(const float* __restrict__ q,
                                               const float* __restrict__ k,
                                               short* __restrict__ qbf,
                                               short* __restrict__ kbf) {
  size_t i = ((size_t)blockIdx.x * 256 + threadIdx.x) * 8;
  const f32x4* qa = (const f32x4*)(q + i);
  const f32x4* ka = (const f32x4*)(k + i);
  f32x4 a0 = __builtin_nontemporal_load(qa);
  f32x4 a1 = __builtin_nontemporal_load(qa + 1);
  f32x4 b0 = __builtin_nontemporal_load(ka);
  f32x4 b1 = __builtin_nontemporal_load(ka + 1);
  s16x8 oq, ok;
  #pragma unroll
  for (int e = 0; e < 4; ++e) {
    oq[e] = f2bf(a0[e]); oq[4 + e] = f2bf(a1[e]);
    ok[e] = f2bf(b0[e]); ok[4 + e] = f2bf(b1[e]);
  }
  *(s16x8*)(qbf + i) = oq;
  *(s16x8*)(kbf + i) = ok;
}

// ---------------- prep: V -> bf16 transposed Vt[bh][d][j] ----------------
__global__ __launch_bounds__(256) void prep_v(const float* __restrict__ v,
                                              short* __restrict__ vt) {
  __shared__ float tile[64][65];
  const int tid = threadIdx.x;
  const int j0 = blockIdx.x * 64;
  const int bh = blockIdx.y;
  const float* vh = v + (size_t)bh * S_ * D_;
  #pragma unroll
  for (int it = 0; it < 16; ++it) {
    int idx = it * 256 + tid;
    int row = idx >> 6, col = idx & 63;
    tile[row][col] = __builtin_nontemporal_load(&vh[(size_t)(j0 + row) * D_ + col]);
  }
  __syncthreads();
  short* vth = vt + (size_t)bh * D_ * S_;
  #pragma unroll
  for (int it = 0; it < 16; ++it) {
    int idx = it * 256 + tid;
    int d = idx >> 6, jj = idx & 63;
    vth[(size_t)d * S_ + j0 + jj] = f2bf(tile[jj][d]);
  }
}

// ---------------- fused single-pass kernel (R9 structure, PLAIN attn stores) ----------------
template <bool PRE>
__global__ __launch_bounds__(512, 2) void attend_fused(
    const float* __restrict__ q, const float* __restrict__ k,
    const float* __restrict__ v, const int* __restrict__ mask,
    const short* __restrict__ qbf, const short* __restrict__ kbf,
    const short* __restrict__ vt,
    float* __restrict__ out, float* __restrict__ attn) {
  __shared__ short strip[16 * PSTR];     // 65792B P-strip; pvred overlays later
  __shared__ float ls_rs[8][16];
  __shared__ float ls_rinv[16];

  const int tid  = threadIdx.x;
  const int wv   = tid >> 6;
  const int lane = tid & 63;
  const int lg   = lane >> 4;
  const int li   = lane & 15;

  // XCD-aware bijective swizzle: 4096 blocks, 8 XCDs -> 4 contiguous heads/XCD
  const unsigned flat = blockIdx.y * gridDim.x + blockIdx.x;
  const unsigned swz  = (flat & 7) * 512 + (flat >> 3);
  const int q0 = (int)(swz & 127) * 16;
  const int bh = (int)(swz >> 7);
  const int b  = bh >> 4;
  const int* mrow = mask + (size_t)b * S_;

  s16x8 qf0, qf1;
  if constexpr (PRE) {
    const short* qr = qbf + ((size_t)bh * S_ + q0 + li) * D_ + lg * 8;
    qf0 = *(const s16x8*)qr;
    qf1 = *(const s16x8*)(qr + 32);
  } else {
    const float* qr = q + ((size_t)bh * S_ + q0 + li) * D_ + lg * 8;
    #pragma unroll
    for (int e = 0; e < 8; ++e) { qf0[e] = f2bf(qr[e]); qf1[e] = f2bf(qr[32 + e]); }
  }

  const short* kbase = PRE ? (kbf + (size_t)bh * S_ * D_) : nullptr;
  s16x8 kf[8];   // pipelined K fragments
  auto ldK = [&](int cc) {
    const int jcc = cc * 512 + wv * 64;
    #pragma unroll
    for (int n = 0; n < 4; ++n) {
      const short* kr = kbase + (size_t)(jcc + n * 16 + li) * D_ + lg * 8;
      kf[2 * n]     = *(const s16x8*)kr;
      kf[2 * n + 1] = *(const s16x8*)(kr + 32);
    }
  };
  if constexpr (PRE) ldK(0);

  float rs[4] = {0.f, 0.f, 0.f, 0.f};
  f32x4 pvacc[4];
  #pragma unroll
  for (int m = 0; m < 4; ++m) pvacc[m] = (f32x4){0.f, 0.f, 0.f, 0.f};

  #pragma unroll
  for (int c = 0; c < 4; ++c) {
    const int jc = c * 512 + wv * 64;

    f32x4 acc[4];
    #pragma unroll
    for (int n = 0; n < 4; ++n) acc[n] = (f32x4){0.f, 0.f, 0.f, 0.f};
    if constexpr (PRE) {
      #pragma unroll
      for (int n = 0; n < 4; ++n) {
        acc[n] = __builtin_amdgcn_mfma_f32_16x16x32_bf16(qf0, kf[2 * n], acc[n], 0, 0, 0);
        acc[n] = __builtin_amdgcn_mfma_f32_16x16x32_bf16(qf1, kf[2 * n + 1], acc[n], 0, 0, 0);
      }
      if (c < 3) ldK(c + 1);   // prefetch hides L2 latency under softcap+PV
    } else {
      #pragma unroll
      for (int n = 0; n < 4; ++n) {
        const float* kr = k + ((size_t)bh * S_ + jc + n * 16 + li) * D_ + lg * 8;
        s16x8 k0, k1;
        #pragma unroll
        for (int e = 0; e < 8; ++e) { k0[e] = f2bf(kr[e]); k1[e] = f2bf(kr[32 + e]); }
        acc[n] = __builtin_amdgcn_mfma_f32_16x16x32_bf16(qf0, k0, acc[n], 0, 0, 0);
        acc[n] = __builtin_amdgcn_mfma_f32_16x16x32_bf16(qf1, k1, acc[n], 0, 0, 0);
      }
    }

    // poly softcap + mask -> P strip (single LDS write)
    #pragma unroll
    for (int n = 0; n < 4; ++n) {
      const int j = jc + n * 16 + li;
      const bool keep = mrow[j] != 0;
      #pragma unroll
      for (int r = 0; r < 4; ++r) {
        float pp = softcap_p(acc[n][r]);
        float pv_ = keep ? pp : 0.f;
        rs[r] += pv_;
        strip[(lg * 4 + r) * PSTR + j] = f2bf(pv_);
      }
    }

    // PV from strip (wave-private columns, no barrier)
    #pragma unroll
    for (int ks = 0; ks < 2; ++ks) {
      s16x8 pa = *(const s16x8*)&strip[li * PSTR + jc + ks * 32 + lg * 8];
      #pragma unroll
      for (int m = 0; m < 4; ++m) {
        s16x8 vb;
        if constexpr (PRE) {
          vb = *(const s16x8*)(vt + ((size_t)bh * D_ + m * 16 + li) * S_ + jc + ks * 32 + lg * 8);
        } else {
          const float* vp = v + (size_t)bh * S_ * D_ + (size_t)(jc + ks * 32 + lg * 8) * D_ + m * 16 + li;
          #pragma unroll
          for (int e = 0; e < 8; ++e) vb[e] = f2bf(vp[(size_t)e * D_]);
        }
        pvacc[m] = __builtin_amdgcn_mfma_f32_16x16x32_bf16(pa, vb, pvacc[m], 0, 0, 0);
      }
    }
  }

  // row sums
  #pragma unroll
  for (int r = 0; r < 4; ++r) {
    #pragma unroll
    for (int m = 1; m < 16; m <<= 1) rs[r] += __shfl_xor(rs[r], m, 64);
  }
  if (li == 0) {
    #pragma unroll
    for (int r = 0; r < 4; ++r) ls_rs[wv][lg * 4 + r] = rs[r];
  }
  __syncthreads();
  if (tid < 16) {
    float ssum = 0.f;
    #pragma unroll
    for (int w = 0; w < 8; ++w) ssum += ls_rs[w][tid];
    ls_rinv[tid] = (ssum > 0.f) ? 1.f / ssum : 0.f;
  }
  __syncthreads();

  // ---- attn = strip * rinv; PLAIN stores (L2 write-combining) ----
  float* abase = attn + ((size_t)bh * S_ + q0) * S_;
  #pragma unroll
  for (int rr = 0; rr < 2; ++rr) {
    const int row = wv * 2 + rr;
    const float rv = ls_rinv[row];
    const short* srow = &strip[row * PSTR];
    float* arow = abase + (size_t)row * S_;
    #pragma unroll
    for (int it = 0; it < 8; ++it) {
      s16x4 pb = *(const s16x4*)&srow[it * 256 + lane * 4];
      f32x4 a;
      a[0] = bf2f(pb[0]) * rv; a[1] = bf2f(pb[1]) * rv;
      a[2] = bf2f(pb[2]) * rv; a[3] = bf2f(pb[3]) * rv;
      *(f32x4*)(arow + it * 256 + lane * 4) = a;
    }
  }

  __syncthreads();   // strip reads done; overlay safe

  float (*pvred)[16][64] = (float (*)[16][64])strip;   // 32KB overlay
  #pragma unroll
  for (int m = 0; m < 4; ++m)
    #pragma unroll
    for (int r = 0; r < 4; ++r)
      pvred[wv][lg * 4 + r][m * 16 + li] = pvacc[m][r];
  __syncthreads();

  #pragma unroll
  for (int h = 0; h < 2; ++h) {
    const int idx = h * 512 + tid;
    const int qq = idx >> 6, d = idx & 63;
    float ssum = 0.f;
    #pragma unroll
    for (int w = 0; w < 8; ++w) ssum += pvred[w][qq][d];
    out[((size_t)bh * S_ + q0 + qq) * D_ + d] = ssum * ls_rinv[qq];
  }
}

extern "C" void kernel_launch(void* const* d_in, const int* in_sizes, int n_in,
                              void* d_out, int out_size, void* d_ws, size_t ws_size,
                              hipStream_t stream) {
  const float* q = (const float*)d_in[0];
  const float* k = (const float*)d_in[1];
  const float* v = (const float*)d_in[2];
  const int* mask = (const int*)d_in[3];

  float* out  = (float*)d_out;
  const size_t nel = (size_t)B_ * H_ * S_ * D_;
  float* attn = out + nel;

  dim3 grid(S_ / 16, B_ * H_);
  const size_t need = nel * 2 * 3;   // Qbf + Kbf + Vt

  if (ws_size >= need) {
    short* qbf = (short*)d_ws;
    short* kbf = qbf + nel;
    short* vtp = kbf + nel;
    prep_qk<<<(int)(nel / (256 * 8)), 256, 0, stream>>>(q, k, qbf, kbf);
    prep_v<<<dim3(S_ / 64, B_ * H_), 256, 0, stream>>>(v, vtp);
    attend_fused<true><<<grid, 512, 0, stream>>>(q, k, v, mask, qbf, kbf, vtp, out, attn);
  } else {
    attend_fused<false><<<grid, 512, 0, stream>>>(q, k, v, mask, nullptr, nullptr, nullptr, out, attn);
  }
}